// Round 8
// baseline (70.223 us; speedup 1.0000x reference)
//
#include <hip/hip_runtime.h>
#include <hip/hip_bf16.h>

typedef float f32x4 __attribute__((ext_vector_type(4)));
typedef short bf16x8 __attribute__((ext_vector_type(8)));

#define LRELU_SLOPE 0.2f
#define SQRT2F 1.4142135623730951f
#define MODSCALE 0.044194173824159216f  // 512^-0.5

#define GLL(SRC, DST)                                                       \
  __builtin_amdgcn_global_load_lds(                                         \
      (const __attribute__((address_space(1))) unsigned int*)(SRC),         \
      (__attribute__((address_space(3))) unsigned int*)(DST), 16, 0, 0)

// ---------------- kernel 1: style  s[b][ci] ----------------
__global__ __launch_bounds__(64) void style_kernel(const float* __restrict__ y,
                                                   const float* __restrict__ mw,
                                                   const float* __restrict__ bias,
                                                   float* __restrict__ s) {
  int ci = blockIdx.x;      // 512 blocks
  int l = threadIdx.x;      // 64 lanes
  const float4* mwr = reinterpret_cast<const float4*>(mw + ci * 512);
  float4 m0 = mwr[2 * l], m1 = mwr[2 * l + 1];
  float acc[8];
#pragma unroll
  for (int b = 0; b < 8; ++b) {
    const float4* yr = reinterpret_cast<const float4*>(y + b * 512);
    float4 y0 = yr[2 * l], y1 = yr[2 * l + 1];
    acc[b] = m0.x * y0.x + m0.y * y0.y + m0.z * y0.z + m0.w * y0.w +
             m1.x * y1.x + m1.y * y1.y + m1.z * y1.z + m1.w * y1.w;
  }
#pragma unroll
  for (int off = 32; off > 0; off >>= 1) {
#pragma unroll
    for (int b = 0; b < 8; ++b) acc[b] += __shfl_xor(acc[b], off, 64);
  }
  if (l < 8) {
    float v = acc[l] * MODSCALE + bias[ci];
    v = v > 0.f ? v : LRELU_SLOPE * v;
    s[l * 512 + ci] = v * SQRT2F;
  }
}

// ---------------- kernel 2: weight prep: wt[t][co][ci] bf16 + wsq[co][ci] ----------------
__global__ __launch_bounds__(256) void wprep_kernel(const float* __restrict__ w,
                                                    __hip_bfloat16* __restrict__ wt,
                                                    float* __restrict__ wsq) {
  int idx = blockIdx.x * 256 + threadIdx.x;  // 262144 = co*512+ci
  const float* p = w + (size_t)idx * 9;
  float v[9];
  float sq = 0.f;
#pragma unroll
  for (int t = 0; t < 9; ++t) {
    v[t] = p[t];
    sq += v[t] * v[t];
  }
  wsq[idx] = sq;
#pragma unroll
  for (int t = 0; t < 9; ++t) wt[t * 262144 + idx] = __float2bfloat16(v[t]);
}

// ---------------- kernel 3: demod  d[b][co] ----------------
__global__ __launch_bounds__(64) void demod_kernel(const float* __restrict__ wsq,
                                                   const float* __restrict__ s,
                                                   float* __restrict__ d) {
  int co = blockIdx.x;  // 512 blocks
  int l = threadIdx.x;
  const float4* qr = reinterpret_cast<const float4*>(wsq + co * 512);
  float4 q0 = qr[2 * l], q1 = qr[2 * l + 1];
  float acc[8];
#pragma unroll
  for (int b = 0; b < 8; ++b) {
    const float4* sr = reinterpret_cast<const float4*>(s + b * 512);
    float4 s0 = sr[2 * l], s1 = sr[2 * l + 1];
    acc[b] = q0.x * s0.x * s0.x + q0.y * s0.y * s0.y + q0.z * s0.z * s0.z +
             q0.w * s0.w * s0.w + q1.x * s1.x * s1.x + q1.y * s1.y * s1.y +
             q1.z * s1.z * s1.z + q1.w * s1.w * s1.w;
  }
#pragma unroll
  for (int off = 32; off > 0; off >>= 1) {
#pragma unroll
    for (int b = 0; b < 8; ++b) acc[b] += __shfl_xor(acc[b], off, 64);
  }
  if (l < 8) d[l * 512 + co] = rsqrtf(acc[l] + 1e-8f);
}

// ---------------- kernel 4: xs prep: NCHW f32 -> padded NHWC bf16, x * s ----------------
__global__ __launch_bounds__(256) void xs_kernel(const float* __restrict__ x,
                                                 const float* __restrict__ s,
                                                 __hip_bfloat16* __restrict__ xsp) {
  // grid: b(8) * h(32) * cc(8) = 2048 blocks of 256
  int bid = blockIdx.x;
  int cc = bid & 7;
  int h = (bid >> 3) & 31;
  int b = bid >> 8;
  int tid = threadIdx.x;
  __shared__ __hip_bfloat16 tile[32][72];  // [w][ci_local], padded

  int cil = tid >> 2;            // 0..63
  int w0 = (tid & 3) * 8;        // 0,8,16,24
  int ci = cc * 64 + cil;
  const float* xp = x + (((size_t)(b * 512 + ci) * 32 + h) << 5) + w0;
  float sv = s[b * 512 + ci];
  float4 a0 = *reinterpret_cast<const float4*>(xp);
  float4 a1 = *reinterpret_cast<const float4*>(xp + 4);
  tile[w0 + 0][cil] = __float2bfloat16(a0.x * sv);
  tile[w0 + 1][cil] = __float2bfloat16(a0.y * sv);
  tile[w0 + 2][cil] = __float2bfloat16(a0.z * sv);
  tile[w0 + 3][cil] = __float2bfloat16(a0.w * sv);
  tile[w0 + 4][cil] = __float2bfloat16(a1.x * sv);
  tile[w0 + 5][cil] = __float2bfloat16(a1.y * sv);
  tile[w0 + 6][cil] = __float2bfloat16(a1.z * sv);
  tile[w0 + 7][cil] = __float2bfloat16(a1.w * sv);
  __syncthreads();

  int wloc = tid >> 3;           // 0..31
  int cj = (tid & 7) * 8;        // 0..56
  int4 v = *reinterpret_cast<const int4*>(&tile[wloc][cj]);
  unsigned off = (unsigned)((b * 34 + h + 1) * 34 + (wloc + 1)) * 512 + cc * 64 + cj;
  *reinterpret_cast<int4*>(xsp + off) = v;
}

// ---------------- kernel 5: conv — halo implicit GEMM, 8 waves, K-split, 3-tap groups ----
// 128pix x 128co tile, 512 threads. kg = wv>>2 owns K-half; (wr,wc) 2x2, acc[4][4] each.
// 24 groups (8 k-chunks x 3 dh-rows); per group: 1 barrier, stage 3 B-slices (+A share),
// compute 3 taps (24 ds_read + 48 MFMA per wave). vmcnt(0) per group (distance = 1 group).
// setprio(1) around MFMA clusters (T5). Cross-kg reduction via LDS at the end.
__global__ __launch_bounds__(512, 2) void conv_kernel(const __hip_bfloat16* __restrict__ xsp,
                                                      const __hip_bfloat16* __restrict__ wt,
                                                      const float* __restrict__ dmod,
                                                      float* __restrict__ out) {
  __shared__ __hip_bfloat16 As_[2][224 * 64];       // 2 x 28 KB (204 halo rows used)
  __shared__ __hip_bfloat16 Bs_[2][3 * 128 * 64];   // 2 super-slots x 48 KB
  const int bid = blockIdx.x;  // 256 blocks
  const int xcd = bid & 7, slot = bid >> 3;         // XCD-aware remap
  const int bm = xcd * 8 + (slot >> 2);
  const int bn = slot & 3;
  const int tid = threadIdx.x;
  const int wv = tid >> 6;
  const int l = tid & 63;
  const int kg = wv >> 2;          // K-group
  const int wr = (wv >> 1) & 1, wc = wv & 1;
  const int bb = bm >> 3;          // batch
  const int h0 = (bm & 7) << 2;    // first output image row of tile

  const int swz = (((l & 7) ^ (l >> 3)) << 3);  // staging pre-swizzle (row&7 == l>>3)
  unsigned boff[2];
#pragma unroll
  for (int j = 0; j < 2; ++j) {
    int row = ((j * 8 + wv) << 3) + (l >> 3);
    boff[j] = (unsigned)((bn << 7) + row) * 512 + swz;
  }
  unsigned ahoff[4];
  int adst[4];
#pragma unroll
  for (int j = 0; j < 4; ++j) {
    int rb = j < 3 ? j * 64 + wv * 8 : 192 + (wv & 3) * 8;  // j=3: wave pairs duplicate
    int r = rb + (l >> 3);                                   // halo row 0..223
    int rc = r > 203 ? 203 : r;                              // rows 204..223 = safe garbage
    int hr = rc / 34, hc = rc - hr * 34;
    ahoff[j] = (unsigned)((bb * 34 + h0 + hr) * 34 + hc) * 512 + (((l & 7) ^ (r & 7)) << 3);
    adst[j] = rb;
  }
  int pb[4];
#pragma unroll
  for (int m = 0; m < 4; ++m)
    pb[m] = ((wr << 1) + (m >> 1)) * 34 + ((m & 1) << 4) + (l & 15);

  f32x4 acc[4][4];
#pragma unroll
  for (int n = 0; n < 4; ++n)
#pragma unroll
    for (int m = 0; m < 4; ++m) acc[n][m] = (f32x4)0.f;

  auto stageB = [&](__hip_bfloat16* Bn, int t, int k0c) {
    const __hip_bfloat16* src = wt + t * 262144 + k0c * 64;
#pragma unroll
    for (int j = 0; j < 2; ++j)
      GLL(src + boff[j], Bn + ((j * 8 + wv) << 9));
  };
  auto stageA1 = [&](__hip_bfloat16* An, int j, int kn) {
    GLL(xsp + ahoff[j] + kn * 64, An + (adst[j] << 6));
  };
  auto phase = [&](const __hip_bfloat16* Aq, const __hip_bfloat16* Bq, int dh, int dw) {
    const int cb = (kg << 2) + (l >> 4);
    bf16x8 af[4], bfr[4];
#pragma unroll
    for (int m = 0; m < 4; ++m) {
      int p = pb[m] + dh * 34 + dw;
      af[m] = *reinterpret_cast<const bf16x8*>(Aq + p * 64 + ((cb ^ (p & 7)) << 3));
    }
#pragma unroll
    for (int n = 0; n < 4; ++n) {
      int row = (wc << 6) + (n << 4) + (l & 15);
      bfr[n] = *reinterpret_cast<const bf16x8*>(Bq + row * 64 + ((cb ^ (l & 7)) << 3));
    }
    __builtin_amdgcn_s_setprio(1);
#pragma unroll
    for (int n = 0; n < 4; ++n)
#pragma unroll
      for (int m = 0; m < 4; ++m)
        acc[n][m] = __builtin_amdgcn_mfma_f32_16x16x32_bf16(bfr[n], af[m], acc[n][m], 0, 0, 0);
    __builtin_amdgcn_s_setprio(0);
  };

#define SB0 __builtin_amdgcn_sched_barrier(0)
#define WAITBAR0                                            \
  asm volatile("s_waitcnt vmcnt(0)" ::: "memory");          \
  __builtin_amdgcn_s_barrier();                             \
  SB0

  // prologue: A halo (k0=0) + B super-slot 0 (taps 0..2)
#pragma unroll
  for (int j = 0; j < 4; ++j) stageA1(&As_[0][0], j, 0);
  SB0;
  stageB(&Bs_[0][0] + 0 * 8192, 0, 0);
  stageB(&Bs_[0][0] + 1 * 8192, 1, 0);
  stageB(&Bs_[0][0] + 2 * 8192, 2, 0);

#pragma unroll 1
  for (int k0 = 0; k0 < 8; ++k0) {
    const __hip_bfloat16* Aq = &As_[k0 & 1][0];
    __hip_bfloat16* An = &As_[(k0 + 1) & 1][0];
    __hip_bfloat16* Br = &Bs_[k0 & 1][0];         // holds taps 0..2 of k0
    __hip_bfloat16* Bo = &Bs_[(k0 & 1) ^ 1][0];   // staging target
    const int kn = k0 + 1;
    // ---- group dh=0: read taps 0..2 from Br; stage taps 3..5 -> Bo, A chunks 0,1 ----
    WAITBAR0;
    stageB(Bo + 0 * 8192, 3, k0);
    stageB(Bo + 1 * 8192, 4, k0);
    stageB(Bo + 2 * 8192, 5, k0);
    if (k0 < 7) { stageA1(An, 0, kn); stageA1(An, 1, kn); }
    SB0;
    phase(Aq, Br + 0 * 8192, 0, 0);
    phase(Aq, Br + 1 * 8192, 0, 1);
    phase(Aq, Br + 2 * 8192, 0, 2);
    // ---- group dh=1: read taps 3..5 from Bo; stage taps 6..8 -> Br, A chunks 2,3 ----
    WAITBAR0;
    stageB(Br + 0 * 8192, 6, k0);
    stageB(Br + 1 * 8192, 7, k0);
    stageB(Br + 2 * 8192, 8, k0);
    if (k0 < 7) { stageA1(An, 2, kn); stageA1(An, 3, kn); }
    SB0;
    phase(Aq, Bo + 0 * 8192, 1, 0);
    phase(Aq, Bo + 1 * 8192, 1, 1);
    phase(Aq, Bo + 2 * 8192, 1, 2);
    // ---- group dh=2: read taps 6..8 from Br; stage next k0's taps 0..2 -> Bo ----
    WAITBAR0;
    if (k0 < 7) {
      stageB(Bo + 0 * 8192, 0, kn);
      stageB(Bo + 1 * 8192, 1, kn);
      stageB(Bo + 2 * 8192, 2, kn);
    }
    SB0;
    phase(Aq, Br + 0 * 8192, 2, 0);
    phase(Aq, Br + 1 * 8192, 2, 1);
    phase(Aq, Br + 2 * 8192, 2, 2);
  }
#undef WAITBAR0
#undef SB0

  // ---- cross-kg reduction via LDS (over Bs_, 96 KB >= 64 KB) ----
  float* red = reinterpret_cast<float*>(&Bs_[0][0]);
  __syncthreads();
  if (kg == 1) {
#pragma unroll
    for (int n = 0; n < 4; ++n)
#pragma unroll
      for (int m = 0; m < 4; ++m)
        *reinterpret_cast<f32x4*>(red + (n * 4 + m) * 1024 + (wv & 3) * 256 + l * 4) =
            acc[n][m];
  }
  __syncthreads();
  if (kg == 0) {
    const int pixbase = ((bm & 7) << 7) + (wr << 6) + (l & 15);
    const int cob = (bn << 7) + (wc << 6) + ((l >> 4) << 2);
    float* ob = out + ((size_t)bb << 19);
    const float* drow = dmod + bb * 512;
#pragma unroll
    for (int n = 0; n < 4; ++n) {
#pragma unroll
      for (int m = 0; m < 4; ++m)
        acc[n][m] += *reinterpret_cast<const f32x4*>(red + (n * 4 + m) * 1024 + wv * 256 + l * 4);
#pragma unroll
      for (int jj = 0; jj < 4; ++jj) {
        const int co = cob + (n << 4) + jj;
        const float dv = drow[co];
        float* orow = ob + ((unsigned)co << 10) + pixbase;
#pragma unroll
        for (int m = 0; m < 4; ++m) orow[m << 4] = acc[n][m][jj] * dv;
      }
    }
  }
}

extern "C" void kernel_launch(void* const* d_in, const int* in_sizes, int n_in,
                              void* d_out, int out_size, void* d_ws, size_t ws_size,
                              hipStream_t stream) {
  (void)in_sizes; (void)n_in; (void)out_size; (void)ws_size;
  const float* x = (const float*)d_in[0];       // [8,512,32,32]
  const float* y = (const float*)d_in[1];       // [8,512]
  const float* w = (const float*)d_in[2];       // [512,512,3,3]
  const float* mw = (const float*)d_in[3];      // [512,512]
  const float* bias = (const float*)d_in[4];    // [512]
  float* out = (float*)d_out;                   // [8,512,32,32]

  char* ws = (char*)d_ws;
  float* s = (float*)(ws + 0);                  // 16 KB
  float* dmod = (float*)(ws + 16384);           // 16 KB
  float* wsq = (float*)(ws + 32768);            // 1 MB
  __hip_bfloat16* wt = (__hip_bfloat16*)(ws + 1081344);    // 9*512*512*2 = 4.5 MB
  __hip_bfloat16* xsp = (__hip_bfloat16*)(ws + 5799936);   // 8*34*34*512*2 = 9.03 MB

  hipMemsetAsync(xsp, 0, 9469952, stream);  // zero padded borders
  style_kernel<<<512, 64, 0, stream>>>(y, mw, bias, s);
  wprep_kernel<<<1024, 256, 0, stream>>>(w, wt, wsq);
  demod_kernel<<<512, 64, 0, stream>>>(wsq, s, dmod);
  xs_kernel<<<2048, 256, 0, stream>>>(x, s, xsp);
  conv_kernel<<<256, 512, 0, stream>>>(xsp, wt, dmod, out);
}